// Round 4
// baseline (96.649 us; speedup 1.0000x reference)
//
#include <hip/hip_runtime.h>

// out = vals[searchsorted(quants[1:], x, left)] for x in (-1e4, 1e4], else x.
// quants = linspace(-1,1,257): quants[k] = -1 + k/128 (exact fp32); vals = relu(quants).
// Closed form: k = clamp(ceil(128x + 128) - 1, 0, 256); out = max(k/128 - 1, 0).
//
// Round-4 structure: FLAT kernel, TWO float4 per thread (no loop).
// Both loads issue back-to-back before any use (2x bytes in flight per wave,
// pure MLP gain); stores never gate loads (flat body, wave retires after).
// Layout: thread t in block b handles float4s [b*512 + t] and [b*512 + 256 + t]
// -> both loads fully coalesced within each wave.

typedef float f4 __attribute__((ext_vector_type(4)));

__device__ __forceinline__ f4 proc4(f4 v) {
    f4 r;
#pragma unroll
    for (int j = 0; j < 4; ++j) {
        float x = v[j];
        float t = fmaf(x, 128.0f, 128.0f);           // 128*(x+1), single rounding
        int k = (int)ceilf(t) - 1;                   // searchsorted-left bucket
        k = k < 0 ? 0 : (k > 256 ? 256 : k);
        float y = fmaxf(fmaf((float)k, 0.0078125f, -1.0f), 0.0f);  // relu(quants[k])
        // guard: outside (-1e4, 1e4] (and NaN) passes through unchanged
        r[j] = (x > -10000.0f && x <= 10000.0f) ? y : x;
    }
    return r;
}

__global__ void __launch_bounds__(256) quant_relu_flat2(
    const f4* __restrict__ in, f4* __restrict__ out, int n4) {
    const int base = blockIdx.x * 512 + threadIdx.x;   // 2 float4 per thread
    const int i0 = base;
    const int i1 = base + 256;
    if (i1 < n4) {
        // hot path: both loads in flight before any use
        f4 v0 = in[i0];
        f4 v1 = in[i1];
        out[i0] = proc4(v0);
        out[i1] = proc4(v1);
    } else {
        if (i0 < n4) out[i0] = proc4(in[i0]);
        if (i1 < n4) out[i1] = proc4(in[i1]);
    }
}

// scalar tail handler (n % 4 != 0; not hit for 64M but stay general)
__global__ void quant_relu_tail(const float* __restrict__ in, float* __restrict__ out,
                                int n_start, int n) {
    int i = n_start + blockIdx.x * blockDim.x + threadIdx.x;
    if (i < n) {
        float x = in[i];
        float t = fmaf(x, 128.0f, 128.0f);
        int k = (int)ceilf(t) - 1;
        k = k < 0 ? 0 : (k > 256 ? 256 : k);
        float y = fmaxf(fmaf((float)k, 0.0078125f, -1.0f), 0.0f);
        out[i] = (x > -10000.0f && x <= 10000.0f) ? y : x;
    }
}

extern "C" void kernel_launch(void* const* d_in, const int* in_sizes, int n_in,
                              void* d_out, int out_size, void* d_ws, size_t ws_size,
                              hipStream_t stream) {
    const float* x = (const float*)d_in[0];   // 64*1024*1024 fp32
    float* out = (float*)d_out;

    const int n = in_sizes[0];
    const int n4 = n >> 2;
    const int tail = n & 3;

    // 512 float4 per block (256 threads x 2)
    const int grid = (n4 + 511) / 512;         // 32768 blocks for 64M elements

    if (grid > 0) {
        quant_relu_flat2<<<grid, 256, 0, stream>>>((const f4*)x, (f4*)out, n4);
    }
    if (tail) {
        quant_relu_tail<<<1, 64, 0, stream>>>(x, out, n4 * 4, n);
    }
}

// Round 5
// 93.021 us; speedup vs baseline: 1.0390x; 1.0390x over previous
//
#include <hip/hip_runtime.h>

// out = vals[searchsorted(quants[1:], x, left)] for x in (-1e4, 1e4], else x.
// quants = linspace(-1,1,257): quants[k] = -1 + k/128 (exact fp32); vals = relu(quants).
// Closed form: k = clamp(ceil(128x + 128) - 1, 0, 256); out = max(k/128 - 1, 0).
//
// FINAL structure (round-3 optimum, reverted after round-4 regression):
// FLAT kernel, ONE float4 per thread, load->compute->store->endpgm.
// Empirical structure search on MI355X:
//   - grid-stride loop + 4x ILP + nt:   110.1 us  (store-drain coupling)
//   - flat, 1 f4/thread:                 91.6 us  <- best (5.86 TB/s, 93% of
//                                                    6.29 TB/s copy ceiling)
//   - flat, 2 f4/thread:                 96.6 us  (longer wave lifetime,
//                                                    slower retire/refill churn)
// Lesson: for pure 1:1 R:W streams, wave-churn latency hiding beats per-wave
// MLP; any pending store held by a live wave costs throughput.

typedef float f4 __attribute__((ext_vector_type(4)));

__device__ __forceinline__ f4 proc4(f4 v) {
    f4 r;
#pragma unroll
    for (int j = 0; j < 4; ++j) {
        float x = v[j];
        float t = fmaf(x, 128.0f, 128.0f);           // 128*(x+1), single rounding
        int k = (int)ceilf(t) - 1;                   // searchsorted-left bucket
        k = k < 0 ? 0 : (k > 256 ? 256 : k);
        float y = fmaxf(fmaf((float)k, 0.0078125f, -1.0f), 0.0f);  // relu(quants[k])
        // guard: outside (-1e4, 1e4] (and NaN) passes through unchanged
        r[j] = (x > -10000.0f && x <= 10000.0f) ? y : x;
    }
    return r;
}

__global__ void __launch_bounds__(256) quant_relu_flat(
    const f4* __restrict__ in, f4* __restrict__ out, int n4) {
    const int i = blockIdx.x * blockDim.x + threadIdx.x;
    if (i < n4) {
        out[i] = proc4(in[i]);
    }
}

// scalar tail handler (n % 4 != 0; not hit for 64M but stay general)
__global__ void quant_relu_tail(const float* __restrict__ in, float* __restrict__ out,
                                int n_start, int n) {
    int i = n_start + blockIdx.x * blockDim.x + threadIdx.x;
    if (i < n) {
        float x = in[i];
        float t = fmaf(x, 128.0f, 128.0f);
        int k = (int)ceilf(t) - 1;
        k = k < 0 ? 0 : (k > 256 ? 256 : k);
        float y = fmaxf(fmaf((float)k, 0.0078125f, -1.0f), 0.0f);
        out[i] = (x > -10000.0f && x <= 10000.0f) ? y : x;
    }
}

extern "C" void kernel_launch(void* const* d_in, const int* in_sizes, int n_in,
                              void* d_out, int out_size, void* d_ws, size_t ws_size,
                              hipStream_t stream) {
    const float* x = (const float*)d_in[0];   // 64*1024*1024 fp32
    float* out = (float*)d_out;

    const int n = in_sizes[0];
    const int n4 = n >> 2;
    const int tail = n & 3;

    const int block = 256;
    const int grid = (n4 + block - 1) / block;   // 65536 blocks for 64M elements

    if (grid > 0) {
        quant_relu_flat<<<grid, block, 0, stream>>>((const f4*)x, (f4*)out, n4);
    }
    if (tail) {
        quant_relu_tail<<<1, 64, 0, stream>>>(x, out, n4 * 4, n);
    }
}